// Round 1
// 843.159 us; speedup vs baseline: 1.3087x; 1.3087x over previous
//
#include <hip/hip_runtime.h>

#define D_MODEL 1024
#define N_HEADS 16
#define N_GROUPS 4
#define D_FF 4096
#define N_EXPERTS 8
#define BATCH 2
#define SEQ 1024
#define DK 64
#define NTOK (BATCH*SEQ)
#define KVD (N_GROUPS*DK)
#define QKVN (D_MODEL + 2*KVD)   // 1536: fused [Wq|Wk|Wv] output width
#define APAD 72                  // attention LDS row stride (64+8)

typedef unsigned short u16;
typedef unsigned int u32;
typedef __attribute__((ext_vector_type(8))) short short8;
typedef __attribute__((ext_vector_type(8))) __bf16 bf16x8;
typedef __attribute__((ext_vector_type(4))) float floatx4;

__device__ __forceinline__ float bf2f(u16 s){ return __uint_as_float(((u32)s)<<16); }
__device__ __forceinline__ u16 f2bf(float f){
  u32 u = __float_as_uint(f);
  u += 0x7fffu + ((u>>16)&1u);
  return (u16)(u>>16);
}
__device__ __forceinline__ floatx4 mfma16(short8 a, short8 b, floatx4 c){
  return __builtin_amdgcn_mfma_f32_16x16x32_bf16(
      __builtin_bit_cast(bf16x8, a), __builtin_bit_cast(bf16x8, b), c, 0, 0, 0);
}
// async global->LDS, 16B/lane. LDS dest = wave-uniform base + lane*16 (m104 semantics).
__device__ __forceinline__ void gload16(const u16* g, u16* l){
  __builtin_amdgcn_global_load_lds(
      (const __attribute__((address_space(1))) u32*)g,
      (__attribute__((address_space(3))) u32*)l, 16, 0, 0);
}

// ---------------- fp32 [K][N] -> bf16 [N][K] transpose-convert (64x64 LDS tile) ----
// Weights must land as [N][K] so GEMM B-fragments are contiguous ds_read_b128.
__global__ __launch_bounds__(256) void k_cvt_t(
    const float* __restrict__ src, u16* __restrict__ dst, int K, int N)
{
  size_t moff = (size_t)blockIdx.z * K * N;   // batched matrices (experts)
  src += moff; dst += moff;
  int k0 = blockIdx.y*64, n0 = blockIdx.x*64;
  __shared__ __align__(16) u16 t[64*72];      // [n][k], +8 pad, rows 144B (16B-aligned)
  int tid = threadIdx.x;
  #pragma unroll
  for (int i=0;i<4;i++){
    int idx = i*256 + tid;          // 1024 float4-quads
    int r = idx>>4;                 // k row 0..63
    int c = (idx&15)*4;             // n col
    float4 v = *(const float4*)(src + (size_t)(k0+r)*N + n0 + c);
    t[(c+0)*72 + r] = f2bf(v.x);
    t[(c+1)*72 + r] = f2bf(v.y);
    t[(c+2)*72 + r] = f2bf(v.z);
    t[(c+3)*72 + r] = f2bf(v.w);
  }
  __syncthreads();
  #pragma unroll
  for (int i=0;i<2;i++){
    int idx = i*256 + tid;          // 512 uint4 stores
    int n = idx>>3;
    int kc = (idx&7)*8;
    *(uint4*)(dst + (size_t)(n0+n)*K + k0 + kc) = *(const uint4*)&t[n*72 + kc];
  }
}

// ---------------- rmsnorm1 + rope (per token), fp32 in -> bf16 out ----------------
__global__ __launch_bounds__(256) void k_rmsnorm_rope(
    const float* __restrict__ x, const float* __restrict__ w, u16* __restrict__ xr)
{
  int tok = blockIdx.x;
  int s = tok & (SEQ-1);
  int tid = threadIdx.x;
  const float* xrow = x + (size_t)tok * D_MODEL;
  __shared__ float red[256];
  float4 v = ((const float4*)xrow)[tid];
  red[tid] = v.x*v.x + v.y*v.y + v.z*v.z + v.w*v.w;
  __syncthreads();
  for (int o=128;o>0;o>>=1){ if(tid<o) red[tid]+=red[tid+o]; __syncthreads(); }
  float inv = rsqrtf(red[0]*(1.0f/D_MODEL) + 1e-6f);
  u16* orow = xr + (size_t)tok * D_MODEL;
  #pragma unroll
  for (int ii=0; ii<2; ii++){
    int i = tid + ii*256;                 // pair index 0..511
    float2 p = ((const float2*)xrow)[i];
    float2 wp = ((const float2*)w)[i];
    float xe = p.x*inv*wp.x;
    float xo = p.y*inv*wp.y;
    float th = __expf(-(float)i * (9.210340371976184f/512.0f));  // 10000^(-i/512)
    float ang = (float)s * th;
    float c = cosf(ang), sn = sinf(ang);
    orow[i]       = f2bf(xe*c - xo*sn);
    orow[i+512]   = f2bf(xe*sn + xo*c);
  }
}

// ---------------- m97-structure GEMM: C[M][N] = A[M][K] @ Bt[N][K]^T, bf16 out -----
// BM=128 BN=128 BK=32, 4 waves (each 64x64), global_load_lds staging, 2 barriers/step.
__global__ __launch_bounds__(256) void k_gemm_t(
    const u16* __restrict__ A, const u16* __restrict__ Bt,
    u16* __restrict__ C, int M, int N, int K)
{
  __shared__ __align__(16) u16 As[128*32];
  __shared__ __align__(16) u16 Bs[128*32];
  int tid = threadIdx.x;
  int wave = tid>>6, lane = tid&63, l15 = lane&15, q = lane>>4;
  int wm = wave>>1, wn = wave&1;
  int m0 = blockIdx.y*128, n0 = blockIdx.x*128;
  // staging: chunk ci = call*256 + wave*64 + lane -> row ci>>2, col (ci&3)*8
  const u16* ap0 = A  + (size_t)(m0 + (tid>>2))*K + (tid&3)*8;
  const u16* ap1 = ap0 + (size_t)64*K;
  const u16* bp0 = Bt + (size_t)(n0 + (tid>>2))*K + (tid&3)*8;
  const u16* bp1 = bp0 + (size_t)64*K;
  u16* asb0 = As + wave*512;          // wave-uniform LDS bases (bytes wave*1024)
  u16* asb1 = As + 2048 + wave*512;
  u16* bsb0 = Bs + wave*512;
  u16* bsb1 = Bs + 2048 + wave*512;
  floatx4 acc[4][4];
  #pragma unroll
  for (int i=0;i<4;i++)
    #pragma unroll
    for (int j=0;j<4;j++) acc[i][j] = (floatx4){0.f,0.f,0.f,0.f};
  for (int k0=0;k0<K;k0+=32){
    __syncthreads();                   // prev-step LDS reads done
    gload16(ap0 + k0, asb0);
    gload16(ap1 + k0, asb1);
    gload16(bp0 + k0, bsb0);
    gload16(bp1 + k0, bsb1);
    __syncthreads();                   // compiler drains vmcnt(0) before barrier
    short8 af[4], bf[4];
    #pragma unroll
    for (int i=0;i<4;i++) af[i] = *(const short8*)&As[(wm*64 + i*16 + l15)*32 + q*8];
    #pragma unroll
    for (int i=0;i<4;i++) bf[i] = *(const short8*)&Bs[(wn*64 + i*16 + l15)*32 + q*8];
    #pragma unroll
    for (int mi=0;mi<4;mi++)
      #pragma unroll
      for (int ni=0;ni<4;ni++)
        acc[mi][ni] = mfma16(af[mi], bf[ni], acc[mi][ni]);
  }
  #pragma unroll
  for (int mi=0;mi<4;mi++)
    #pragma unroll
    for (int ni=0;ni<4;ni++)
      #pragma unroll
      for (int r=0;r<4;r++){
        int row = m0 + wm*64 + mi*16 + q*4 + r;   // C/D: row=(lane>>4)*4+reg, col=lane&15
        int col = n0 + wn*64 + ni*16 + l15;
        C[(size_t)row*N + col] = f2bf(acc[mi][ni][r]);
      }
}

// ---------------- same GEMM + fp32 residual -> fp32 h (acc) AND out ---------------
__global__ __launch_bounds__(256) void k_gemm_resid(
    const u16* __restrict__ A, const u16* __restrict__ Bt,
    const float* __restrict__ resid, float* __restrict__ hacc,
    float* __restrict__ out, int M, int N, int K)
{
  __shared__ __align__(16) u16 As[128*32];
  __shared__ __align__(16) u16 Bs[128*32];
  int tid = threadIdx.x;
  int wave = tid>>6, lane = tid&63, l15 = lane&15, q = lane>>4;
  int wm = wave>>1, wn = wave&1;
  int m0 = blockIdx.y*128, n0 = blockIdx.x*128;
  const u16* ap0 = A  + (size_t)(m0 + (tid>>2))*K + (tid&3)*8;
  const u16* ap1 = ap0 + (size_t)64*K;
  const u16* bp0 = Bt + (size_t)(n0 + (tid>>2))*K + (tid&3)*8;
  const u16* bp1 = bp0 + (size_t)64*K;
  u16* asb0 = As + wave*512;
  u16* asb1 = As + 2048 + wave*512;
  u16* bsb0 = Bs + wave*512;
  u16* bsb1 = Bs + 2048 + wave*512;
  floatx4 acc[4][4];
  #pragma unroll
  for (int i=0;i<4;i++)
    #pragma unroll
    for (int j=0;j<4;j++) acc[i][j] = (floatx4){0.f,0.f,0.f,0.f};
  for (int k0=0;k0<K;k0+=32){
    __syncthreads();
    gload16(ap0 + k0, asb0);
    gload16(ap1 + k0, asb1);
    gload16(bp0 + k0, bsb0);
    gload16(bp1 + k0, bsb1);
    __syncthreads();
    short8 af[4], bf[4];
    #pragma unroll
    for (int i=0;i<4;i++) af[i] = *(const short8*)&As[(wm*64 + i*16 + l15)*32 + q*8];
    #pragma unroll
    for (int i=0;i<4;i++) bf[i] = *(const short8*)&Bs[(wn*64 + i*16 + l15)*32 + q*8];
    #pragma unroll
    for (int mi=0;mi<4;mi++)
      #pragma unroll
      for (int ni=0;ni<4;ni++)
        acc[mi][ni] = mfma16(af[mi], bf[ni], acc[mi][ni]);
  }
  #pragma unroll
  for (int mi=0;mi<4;mi++)
    #pragma unroll
    for (int ni=0;ni<4;ni++)
      #pragma unroll
      for (int r=0;r<4;r++){
        int row = m0 + wm*64 + mi*16 + q*4 + r;
        int col = n0 + wn*64 + ni*16 + l15;
        size_t idx = (size_t)row*N + col;
        float v = acc[mi][ni][r] + resid[idx];
        hacc[idx] = v;
        out[idx]  = v;     // moe2 atomically accumulates expert output on top
      }
}

// ---------------- V transpose: qkv V-slice -> Vt[b][g][d][s] (LDS-tiled) ----------
__global__ __launch_bounds__(256) void k_vtrans(
    const u16* __restrict__ qkv, u16* __restrict__ Vt)
{
  int st = blockIdx.x;          // s-tile (SEQ/64)
  int bg = blockIdx.y;          // b*4+g
  int b = bg >> 2, g = bg & 3;
  int tid = threadIdx.x;
  __shared__ u16 tile[64*APAD];
  #pragma unroll
  for (int i=0;i<2;i++){
    int idx = i*256 + tid;
    int srow = idx >> 3, cch = (idx&7)*8;
    uint4 v = *(const uint4*)(qkv + (size_t)(b*SEQ + st*64 + srow)*QKVN
                              + D_MODEL + KVD + g*64 + cch);
    *(uint4*)&tile[srow*APAD + cch] = v;
  }
  __syncthreads();
  #pragma unroll
  for (int i=0;i<2;i++){
    int idx = i*256 + tid;
    int drow = idx >> 3, sch = (idx&7)*8;
    u16 tmp[8];
    #pragma unroll
    for (int j=0;j<8;j++) tmp[j] = tile[(sch+j)*APAD + drow];
    *(uint4*)(Vt + ((size_t)(bg*64 + drow))*SEQ + st*64 + sch) = *(uint4*)tmp;
  }
}

// ---------------- flash attention: 64-row Q-tile per block, MFMA QK^T & PV --------
__global__ __launch_bounds__(256) void k_attn_flash(
    const u16* __restrict__ qkv, const u16* __restrict__ Vt, u16* __restrict__ O)
{
  int qt = blockIdx.x, h = blockIdx.y, b = blockIdx.z;
  int g = h >> 2;
  int tid = threadIdx.x, wave = tid>>6, lane = tid&63, l15 = lane&15, q = lane>>4;
  __shared__ u16 Ks[64*APAD];
  __shared__ u16 Vs[64*APAD];        // transposed V tile: [d][key]
  __shared__ u16 Ps[4*16*APAD];      // per-wave P buffer

  int qbase = qt*64;
  const u16* qrow = qkv + (size_t)(b*SEQ + qbase + wave*16 + l15)*QKVN + h*64;
  short8 qa0 = *(const short8*)(qrow + q*8);
  short8 qa1 = *(const short8*)(qrow + 32 + q*8);

  floatx4 Of[4];
  #pragma unroll
  for (int nt=0;nt<4;nt++) Of[nt] = (floatx4){0.f,0.f,0.f,0.f};
  float mrun[4], lrun[4];
  #pragma unroll
  for (int r=0;r<4;r++){ mrun[r] = -1e30f; lrun[r] = 0.f; }

  for (int t=0; t<=qt; ++t){
    int kbase = t*64;
    __syncthreads();
    #pragma unroll
    for (int i=0;i<2;i++){
      int idx = i*256 + tid;
      int row = idx >> 3, cch = (idx&7)*8;
      uint4 kv = *(const uint4*)(qkv + (size_t)(b*SEQ + kbase + row)*QKVN
                                 + D_MODEL + g*64 + cch);
      *(uint4*)&Ks[row*APAD + cch] = kv;
      uint4 vv = *(const uint4*)(Vt + ((size_t)((b*4+g)*64 + row))*SEQ + kbase + cch);
      *(uint4*)&Vs[row*APAD + cch] = vv;
    }
    __syncthreads();

    floatx4 Sf[4];
    #pragma unroll
    for (int jt=0;jt<4;jt++){
      short8 bf0 = *(const short8*)&Ks[(jt*16+l15)*APAD + q*8];
      short8 bf1 = *(const short8*)&Ks[(jt*16+l15)*APAD + 32 + q*8];
      Sf[jt] = mfma16(qa0, bf0, (floatx4){0.f,0.f,0.f,0.f});
      Sf[jt] = mfma16(qa1, bf1, Sf[jt]);
    }
    bool maskt = (t == qt);
    #pragma unroll
    for (int r=0;r<4;r++){
      float s0 = Sf[0][r]*0.125f, s1 = Sf[1][r]*0.125f,
            s2 = Sf[2][r]*0.125f, s3 = Sf[3][r]*0.125f;
      if (maskt){
        int qg = qbase + wave*16 + q*4 + r;
        if (kbase +      l15 > qg) s0 = -1e30f;
        if (kbase + 16 + l15 > qg) s1 = -1e30f;
        if (kbase + 32 + l15 > qg) s2 = -1e30f;
        if (kbase + 48 + l15 > qg) s3 = -1e30f;
      }
      float mx = fmaxf(fmaxf(s0,s1), fmaxf(s2,s3));
      #pragma unroll
      for (int o=1;o<16;o<<=1) mx = fmaxf(mx, __shfl_xor(mx, o, 64));
      float mc = fmaxf(mrun[r], mx);
      float alpha = __expf(mrun[r]-mc);
      float p0 = __expf(s0-mc), p1 = __expf(s1-mc), p2 = __expf(s2-mc), p3 = __expf(s3-mc);
      float rs = p0+p1+p2+p3;
      #pragma unroll
      for (int o=1;o<16;o<<=1) rs += __shfl_xor(rs, o, 64);
      lrun[r] = lrun[r]*alpha + rs;
      mrun[r] = mc;
      #pragma unroll
      for (int nt=0;nt<4;nt++) Of[nt][r] *= alpha;
      int prow = wave*16*APAD + (q*4+r)*APAD;
      Ps[prow +      l15] = f2bf(p0);
      Ps[prow + 16 + l15] = f2bf(p1);
      Ps[prow + 32 + l15] = f2bf(p2);
      Ps[prow + 48 + l15] = f2bf(p3);
    }
    #pragma unroll
    for (int ks=0;ks<2;ks++){
      short8 pa = *(const short8*)&Ps[wave*16*APAD + l15*APAD + ks*32 + q*8];
      #pragma unroll
      for (int nt=0;nt<4;nt++){
        short8 vb = *(const short8*)&Vs[(nt*16+l15)*APAD + ks*32 + q*8];
        Of[nt] = mfma16(pa, vb, Of[nt]);
      }
    }
  }
  #pragma unroll
  for (int r=0;r<4;r++){
    float linv = 1.0f / lrun[r];
    int row = b*SEQ + qbase + wave*16 + q*4 + r;
    #pragma unroll
    for (int nt=0;nt<4;nt++){
      O[(size_t)row*D_MODEL + h*64 + nt*16 + l15] = f2bf(Of[nt][r]*linv);
    }
  }
}

// ---------------- rmsnorm2 (fp32 in, bf16 out) ----------------
__global__ __launch_bounds__(256) void k_rmsnorm2(
    const float* __restrict__ hacc, const float* __restrict__ w, u16* __restrict__ hn)
{
  int tok = blockIdx.x, tid = threadIdx.x;
  float4 v = ((const float4*)(hacc + (size_t)tok*D_MODEL))[tid];
  __shared__ float red[256];
  red[tid] = v.x*v.x + v.y*v.y + v.z*v.z + v.w*v.w;
  __syncthreads();
  for (int o=128;o>0;o>>=1){ if(tid<o) red[tid]+=red[tid+o]; __syncthreads(); }
  float inv = rsqrtf(red[0]*(1.0f/D_MODEL) + 1e-6f);
  int i = tid*4;
  float4 wv = ((const float4*)w)[tid];
  u16* orow = hn + (size_t)tok*D_MODEL;
  orow[i+0] = f2bf(v.x*inv*wv.x);
  orow[i+1] = f2bf(v.y*inv*wv.y);
  orow[i+2] = f2bf(v.z*inv*wv.z);
  orow[i+3] = f2bf(v.w*inv*wv.w);
}

// ---------------- router: one wave per token, FULL FP32 ----------------
__global__ __launch_bounds__(64) void k_router(
    const float* __restrict__ hacc, const float* __restrict__ w2,
    const float* __restrict__ rw, const float* __restrict__ rb,
    int* __restrict__ topi, float* __restrict__ topw)
{
  int tok = blockIdx.x, lane = threadIdx.x;
  const float* xrow = hacc + (size_t)tok*D_MODEL;
  float ss = 0.f;
  #pragma unroll
  for (int ii=0; ii<4; ii++){
    float4 v = ((const float4*)xrow)[lane + ii*64];
    ss += v.x*v.x + v.y*v.y + v.z*v.z + v.w*v.w;
  }
  #pragma unroll
  for (int o=32;o>0;o>>=1) ss += __shfl_down(ss, o, 64);
  ss = __shfl(ss, 0, 64);
  float inv = rsqrtf(ss*(1.0f/D_MODEL) + 1e-6f);
  float accv[8] = {0.f,0.f,0.f,0.f,0.f,0.f,0.f,0.f};
  for (int d = lane; d < D_MODEL; d += 64){
    float xv = xrow[d]*inv*w2[d];
    float4 r0 = ((const float4*)(rw + (size_t)d*8))[0];
    float4 r1 = ((const float4*)(rw + (size_t)d*8))[1];
    accv[0] += xv*r0.x; accv[1] += xv*r0.y;
    accv[2] += xv*r0.z; accv[3] += xv*r0.w;
    accv[4] += xv*r1.x; accv[5] += xv*r1.y;
    accv[6] += xv*r1.z; accv[7] += xv*r1.w;
  }
  #pragma unroll
  for (int e=0;e<8;e++){
    #pragma unroll
    for (int o=32;o>0;o>>=1) accv[e] += __shfl_down(accv[e], o, 64);
  }
  if (lane==0){
    float lg[8];
    #pragma unroll
    for (int e=0;e<8;e++) lg[e] = accv[e] + rb[e];
    int i0=0; float v0=lg[0];
    for (int e=1;e<8;e++) if (lg[e]>v0){v0=lg[e]; i0=e;}
    int i1=-1; float v1=-1e30f;
    for (int e=0;e<8;e++) if (e!=i0 && lg[e]>v1){v1=lg[e]; i1=e;}
    float e1 = __expf(v1-v0);
    float wsum = 1.f + e1;
    topi[tok*2+0]=i0; topi[tok*2+1]=i1;
    topw[tok*2+0]=1.f/wsum; topw[tok*2+1]=e1/wsum;
  }
}

// ---------------- pack: per-expert packed token lists (single block) --------------
__global__ __launch_bounds__(256) void k_pack(
    const int* __restrict__ topi, const float* __restrict__ topw,
    int* __restrict__ off, int* __restrict__ perm, float* __restrict__ pw)
{
  __shared__ int cnt[8], cur[8], offs[9];
  int tid = threadIdx.x;
  if (tid<8) cnt[tid]=0;
  __syncthreads();
  for (int i=tid;i<NTOK*2;i+=256) atomicAdd(&cnt[topi[i]],1);
  __syncthreads();
  if (tid==0){
    int s=0;
    for (int e=0;e<8;e++){ offs[e]=s; s+=cnt[e]; }
    offs[8]=s;
    for (int e=0;e<9;e++) off[e]=offs[e];
  }
  __syncthreads();
  if (tid<8) cur[tid]=offs[tid];
  __syncthreads();
  for (int i=tid;i<NTOK*2;i+=256){
    int e = topi[i];
    int pos = atomicAdd(&cur[e],1);
    perm[pos] = i>>1;
    pw[pos]   = topw[i];
  }
}

// ---------------- MoE stage1: H = silu(Xg@W1+b1)*(Xg@W2+b2), gathered rows --------
// BM=128 BN=64 dual-B; 4 waves each own 64x32 per matrix (acc 4x2 x2 = 64 VGPR).
__global__ __launch_bounds__(256) void k_moe1(
    const u16* __restrict__ hn,
    const u16* __restrict__ W1t, const float* __restrict__ b1,
    const u16* __restrict__ W2t, const float* __restrict__ b2,
    const int* __restrict__ off, const int* __restrict__ perm,
    u16* __restrict__ H)
{
  int e = blockIdx.z;
  int base = off[e], cnte = off[e+1]-base;
  int mt = blockIdx.y;
  if (mt*128 >= cnte) return;
  int n0 = blockIdx.x*64;
  __shared__ __align__(16) u16 As[128*32];
  __shared__ __align__(16) u16 B1s[64*32];
  __shared__ __align__(16) u16 B2s[64*32];
  int tid = threadIdx.x;
  int wave = tid>>6, lane = tid&63, l15 = lane&15, q = lane>>4;
  int wm = wave>>1, wn = wave&1;
  // gathered A rows: per-lane global addr is legal with global_load_lds;
  // OOB rows read token 0 (safe) and are masked at the epilogue.
  int r0 = mt*128 + (tid>>2), r1 = r0 + 64;
  int t0 = (r0 < cnte) ? perm[base+r0] : 0;
  int t1 = (r1 < cnte) ? perm[base+r1] : 0;
  const u16* ap0 = hn + (size_t)t0*D_MODEL + (tid&3)*8;
  const u16* ap1 = hn + (size_t)t1*D_MODEL + (tid&3)*8;
  const u16* b1p = W1t + (size_t)e*D_FF*D_MODEL + (size_t)(n0 + (tid>>2))*D_MODEL + (tid&3)*8;
  const u16* b2p = W2t + (size_t)e*D_FF*D_MODEL + (size_t)(n0 + (tid>>2))*D_MODEL + (tid&3)*8;
  u16* asb0 = As + wave*512;
  u16* asb1 = As + 2048 + wave*512;
  u16* b1sb = B1s + wave*512;
  u16* b2sb = B2s + wave*512;
  floatx4 acc1[4][2], acc2[4][2];
  #pragma unroll
  for (int i=0;i<4;i++)
    #pragma unroll
    for (int j=0;j<2;j++){ acc1[i][j]=(floatx4){0.f,0.f,0.f,0.f}; acc2[i][j]=(floatx4){0.f,0.f,0.f,0.f}; }
  for (int k0=0;k0<D_MODEL;k0+=32){
    __syncthreads();
    gload16(ap0 + k0, asb0);
    gload16(ap1 + k0, asb1);
    gload16(b1p + k0, b1sb);
    gload16(b2p + k0, b2sb);
    __syncthreads();
    short8 af[4], f1[2], f2[2];
    #pragma unroll
    for (int i=0;i<4;i++) af[i] = *(const short8*)&As[(wm*64 + i*16 + l15)*32 + q*8];
    #pragma unroll
    for (int i=0;i<2;i++){
      f1[i] = *(const short8*)&B1s[(wn*32 + i*16 + l15)*32 + q*8];
      f2[i] = *(const short8*)&B2s[(wn*32 + i*16 + l15)*32 + q*8];
    }
    #pragma unroll
    for (int mi=0;mi<4;mi++)
      #pragma unroll
      for (int ni=0;ni<2;ni++){
        acc1[mi][ni] = mfma16(af[mi], f1[ni], acc1[mi][ni]);
        acc2[mi][ni] = mfma16(af[mi], f2[ni], acc2[mi][ni]);
      }
  }
  #pragma unroll
  for (int mi=0;mi<4;mi++)
    #pragma unroll
    for (int ni=0;ni<2;ni++)
      #pragma unroll
      for (int r=0;r<4;r++){
        int rloc = wm*64 + mi*16 + q*4 + r;
        int grow = mt*128 + rloc;
        if (grow < cnte){
          int col = n0 + wn*32 + ni*16 + l15;
          float h1 = acc1[mi][ni][r] + b1[e*D_FF+col];
          float h2 = acc2[mi][ni][r] + b2[e*D_FF+col];
          float sil = h1 / (1.f + __expf(-h1));
          H[(size_t)(base + grow)*D_FF + col] = f2bf(h2*sil);
        }
      }
}

// ---------------- MoE stage2: out[token] += w * (H@W3 + b3) -----------------------
__global__ __launch_bounds__(256) void k_moe2(
    const u16* __restrict__ H, const u16* __restrict__ W3t, const float* __restrict__ b3,
    const int* __restrict__ off, const int* __restrict__ perm, const float* __restrict__ pw,
    float* __restrict__ out)
{
  int e = blockIdx.z;
  int base = off[e], cnte = off[e+1]-base;
  int mt = blockIdx.y;
  if (mt*128 >= cnte) return;
  int n0 = blockIdx.x*128;
  __shared__ __align__(16) u16 As[128*32];
  __shared__ __align__(16) u16 Bs[128*32];
  int tid = threadIdx.x;
  int wave = tid>>6, lane = tid&63, l15 = lane&15, q = lane>>4;
  int wm = wave>>1, wn = wave&1;
  // H rows are packed contiguous; overread past cnte stays inside workspace, masked.
  const u16* ap0 = H + (size_t)(base + mt*128 + (tid>>2))*D_FF + (tid&3)*8;
  const u16* ap1 = ap0 + (size_t)64*D_FF;
  const u16* bp0 = W3t + (size_t)e*D_MODEL*D_FF + (size_t)(n0 + (tid>>2))*D_FF + (tid&3)*8;
  const u16* bp1 = bp0 + (size_t)64*D_FF;
  u16* asb0 = As + wave*512;
  u16* asb1 = As + 2048 + wave*512;
  u16* bsb0 = Bs + wave*512;
  u16* bsb1 = Bs + 2048 + wave*512;
  floatx4 acc[4][4];
  #pragma unroll
  for (int i=0;i<4;i++)
    #pragma unroll
    for (int j=0;j<4;j++) acc[i][j] = (floatx4){0.f,0.f,0.f,0.f};
  for (int k0=0;k0<D_FF;k0+=32){
    __syncthreads();
    gload16(ap0 + k0, asb0);
    gload16(ap1 + k0, asb1);
    gload16(bp0 + k0, bsb0);
    gload16(bp1 + k0, bsb1);
    __syncthreads();
    short8 af[4], bf[4];
    #pragma unroll
    for (int i=0;i<4;i++) af[i] = *(const short8*)&As[(wm*64 + i*16 + l15)*32 + q*8];
    #pragma unroll
    for (int i=0;i<4;i++) bf[i] = *(const short8*)&Bs[(wn*64 + i*16 + l15)*32 + q*8];
    #pragma unroll
    for (int mi=0;mi<4;mi++)
      #pragma unroll
      for (int ni=0;ni<4;ni++)
        acc[mi][ni] = mfma16(af[mi], bf[ni], acc[mi][ni]);
  }
  #pragma unroll
  for (int mi=0;mi<4;mi++)
    #pragma unroll
    for (int ni=0;ni<4;ni++)
      #pragma unroll
      for (int r=0;r<4;r++){
        int grow = mt*128 + wm*64 + mi*16 + q*4 + r;
        if (grow < cnte){
          int col = n0 + wn*64 + ni*16 + l15;
          int tok = perm[base+grow];
          float wgt = pw[base+grow];
          float val = acc[mi][ni][r] + b3[e*D_MODEL+col];
          atomicAdd(out + (size_t)tok*D_MODEL + col, wgt*val);
        }
      }
}

extern "C" void kernel_launch(void* const* d_in, const int* in_sizes, int n_in,
                              void* d_out, int out_size, void* d_ws, size_t ws_size,
                              hipStream_t stream)
{
  const float* x   = (const float*)d_in[0];
  const float* n1w = (const float*)d_in[1];
  const float* Wq  = (const float*)d_in[2];
  const float* Wk  = (const float*)d_in[3];
  const float* Wv  = (const float*)d_in[4];
  const float* Wo  = (const float*)d_in[5];
  const float* n2w = (const float*)d_in[6];
  const float* rw  = (const float*)d_in[7];
  const float* rb  = (const float*)d_in[8];
  const float* W1  = (const float*)d_in[9];
  const float* b1  = (const float*)d_in[10];
  const float* W2  = (const float*)d_in[11];
  const float* b2  = (const float*)d_in[12];
  const float* W3  = (const float*)d_in[13];
  const float* b3  = (const float*)d_in[14];
  float* out = (float*)d_out;

  char* p = (char*)d_ws;
  auto alloc = [&](size_t bytes)->char*{
    char* r = p; p += (bytes + 255) & ~(size_t)255; return r;
  };
  u16*   xr   = (u16*)  alloc((size_t)NTOK*D_MODEL*2);
  u16*   qkv  = (u16*)  alloc((size_t)NTOK*QKVN*2);    // fused [Q|K|V] activations
  u16*   Vt   = (u16*)  alloc((size_t)NTOK*KVD*2);     // transposed V: [b][g][d][s]
  u16*   attn = (u16*)  alloc((size_t)NTOK*D_MODEL*2);
  u16*   hn   = (u16*)  alloc((size_t)NTOK*D_MODEL*2);
  float* acc  = (float*)alloc((size_t)NTOK*D_MODEL*4);
  int*   topi = (int*)  alloc((size_t)NTOK*2*4);
  float* topw = (float*)alloc((size_t)NTOK*2*4);
  int*   off  = (int*)  alloc(64);
  int*   perm = (int*)  alloc((size_t)NTOK*2*4);
  float* pw   = (float*)alloc((size_t)NTOK*2*4);
  u16*   H    = (u16*)  alloc((size_t)NTOK*2*D_FF*2);
  // transposed bf16 weight copies [N][K]
  u16*   Wqkvt= (u16*)  alloc((size_t)QKVN*D_MODEL*2);
  u16*   Wot  = (u16*)  alloc((size_t)D_MODEL*D_MODEL*2);
  u16*   W1t  = (u16*)  alloc((size_t)N_EXPERTS*D_MODEL*D_FF*2);
  u16*   W2t  = (u16*)  alloc((size_t)N_EXPERTS*D_MODEL*D_FF*2);
  u16*   W3t  = (u16*)  alloc((size_t)N_EXPERTS*D_FF*D_MODEL*2);

  // 0. weight transpose-convert fp32 [K][N] -> bf16 [N][K]; Q|K|V fused into one
  k_cvt_t<<<dim3(D_MODEL/64, D_MODEL/64, 1), 256, 0, stream>>>(Wq, Wqkvt, D_MODEL, D_MODEL);
  k_cvt_t<<<dim3(KVD/64,     D_MODEL/64, 1), 256, 0, stream>>>(Wk, Wqkvt + (size_t)D_MODEL*D_MODEL, D_MODEL, KVD);
  k_cvt_t<<<dim3(KVD/64,     D_MODEL/64, 1), 256, 0, stream>>>(Wv, Wqkvt + (size_t)(D_MODEL+KVD)*D_MODEL, D_MODEL, KVD);
  k_cvt_t<<<dim3(D_MODEL/64, D_MODEL/64, 1), 256, 0, stream>>>(Wo, Wot, D_MODEL, D_MODEL);
  k_cvt_t<<<dim3(D_FF/64,    D_MODEL/64, N_EXPERTS), 256, 0, stream>>>(W1, W1t, D_MODEL, D_FF);
  k_cvt_t<<<dim3(D_FF/64,    D_MODEL/64, N_EXPERTS), 256, 0, stream>>>(W2, W2t, D_MODEL, D_FF);
  k_cvt_t<<<dim3(D_MODEL/64, D_FF/64,    N_EXPERTS), 256, 0, stream>>>(W3, W3t, D_FF, D_MODEL);

  // 1. norm1 + rope
  k_rmsnorm_rope<<<NTOK, 256, 0, stream>>>(x, n1w, xr);
  // 2. fused QKV projection (one GEMM, N=1536)
  k_gemm_t<<<dim3(QKVN/128, NTOK/128), 256, 0, stream>>>(xr, Wqkvt, qkv, NTOK, QKVN, D_MODEL);
  // 3. attention (flash, MFMA)
  k_vtrans<<<dim3(SEQ/64, BATCH*N_GROUPS), 256, 0, stream>>>(qkv, Vt);
  k_attn_flash<<<dim3(SEQ/64, N_HEADS, BATCH), 256, 0, stream>>>(qkv, Vt, attn);
  // 4. out proj + residual -> h (fp32, to acc for norm/router AND to out for moe2)
  k_gemm_resid<<<dim3(D_MODEL/128, NTOK/128), 256, 0, stream>>>(attn, Wot, x, acc, out, NTOK, D_MODEL, D_MODEL);
  // 5. norm2 (bf16 activations for expert GEMMs)
  k_rmsnorm2<<<NTOK, 256, 0, stream>>>(acc, n2w, hn);
  // 6. router (fp32, from fp32 residual) + pack
  k_router<<<NTOK, 64, 0, stream>>>(acc, n2w, rw, rb, topi, topw);
  k_pack<<<1, 256, 0, stream>>>(topi, topw, off, perm, pw);
  // 7. expert FFN (moe2 accumulates into out on top of residual)
  k_moe1<<<dim3(D_FF/64,    32, N_EXPERTS), 256, 0, stream>>>(hn, W1t, b1, W2t, b2, off, perm, H);
  k_moe2<<<dim3(D_MODEL/128, 32, N_EXPERTS), 256, 0, stream>>>(H, W3t, b3, off, perm, pw, out);
}

// Round 2
// 786.760 us; speedup vs baseline: 1.4025x; 1.0717x over previous
//
#include <hip/hip_runtime.h>

#define D_MODEL 1024
#define N_HEADS 16
#define N_GROUPS 4
#define D_FF 4096
#define N_EXPERTS 8
#define BATCH 2
#define SEQ 1024
#define DK 64
#define NTOK (BATCH*SEQ)
#define KVD (N_GROUPS*DK)
#define QKVN (D_MODEL + 2*KVD)   // 1536: fused [Wq|Wk|Wv] output width
#define APAD 72                  // attention LDS row stride (64+8)

typedef unsigned short u16;
typedef unsigned int u32;
typedef __attribute__((ext_vector_type(8))) short short8;
typedef __attribute__((ext_vector_type(8))) __bf16 bf16x8;
typedef __attribute__((ext_vector_type(4))) float floatx4;

__device__ __forceinline__ float bf2f(u16 s){ return __uint_as_float(((u32)s)<<16); }
__device__ __forceinline__ u16 f2bf(float f){
  u32 u = __float_as_uint(f);
  u += 0x7fffu + ((u>>16)&1u);
  return (u16)(u>>16);
}
__device__ __forceinline__ floatx4 mfma16(short8 a, short8 b, floatx4 c){
  return __builtin_amdgcn_mfma_f32_16x16x32_bf16(
      __builtin_bit_cast(bf16x8, a), __builtin_bit_cast(bf16x8, b), c, 0, 0, 0);
}
// async global->LDS, 16B/lane. LDS dest = wave-uniform base + lane*16 (m104 semantics).
__device__ __forceinline__ void gload16(const u16* g, u16* l){
  __builtin_amdgcn_global_load_lds(
      (const __attribute__((address_space(1))) u32*)g,
      (__attribute__((address_space(3))) u32*)l, 16, 0, 0);
}

// ---------------- fp32 [K][N] -> bf16 [N][K] transpose-convert (64x64 LDS tile) ----
__global__ __launch_bounds__(256) void k_cvt_t(
    const float* __restrict__ src, u16* __restrict__ dst, int K, int N)
{
  size_t moff = (size_t)blockIdx.z * K * N;   // batched matrices (experts)
  src += moff; dst += moff;
  int k0 = blockIdx.y*64, n0 = blockIdx.x*64;
  __shared__ __align__(16) u16 t[64*72];      // [n][k], +8 pad
  int tid = threadIdx.x;
  #pragma unroll
  for (int i=0;i<4;i++){
    int idx = i*256 + tid;          // 1024 float4-quads
    int r = idx>>4;                 // k row 0..63
    int c = (idx&15)*4;             // n col
    float4 v = *(const float4*)(src + (size_t)(k0+r)*N + n0 + c);
    t[(c+0)*72 + r] = f2bf(v.x);
    t[(c+1)*72 + r] = f2bf(v.y);
    t[(c+2)*72 + r] = f2bf(v.z);
    t[(c+3)*72 + r] = f2bf(v.w);
  }
  __syncthreads();
  #pragma unroll
  for (int i=0;i<2;i++){
    int idx = i*256 + tid;          // 512 uint4 stores
    int n = idx>>3;
    int kc = (idx&7)*8;
    *(uint4*)(dst + (size_t)(n0+n)*K + k0 + kc) = *(const uint4*)&t[n*72 + kc];
  }
}

// ---------------- rmsnorm1 + rope (per token), fp32 in -> bf16 out ----------------
__global__ __launch_bounds__(256) void k_rmsnorm_rope(
    const float* __restrict__ x, const float* __restrict__ w, u16* __restrict__ xr)
{
  int tok = blockIdx.x;
  int s = tok & (SEQ-1);
  int tid = threadIdx.x;
  const float* xrow = x + (size_t)tok * D_MODEL;
  __shared__ float red[256];
  float4 v = ((const float4*)xrow)[tid];
  red[tid] = v.x*v.x + v.y*v.y + v.z*v.z + v.w*v.w;
  __syncthreads();
  for (int o=128;o>0;o>>=1){ if(tid<o) red[tid]+=red[tid+o]; __syncthreads(); }
  float inv = rsqrtf(red[0]*(1.0f/D_MODEL) + 1e-6f);
  u16* orow = xr + (size_t)tok * D_MODEL;
  #pragma unroll
  for (int ii=0; ii<2; ii++){
    int i = tid + ii*256;                 // pair index 0..511
    float2 p = ((const float2*)xrow)[i];
    float2 wp = ((const float2*)w)[i];
    float xe = p.x*inv*wp.x;
    float xo = p.y*inv*wp.y;
    float th = __expf(-(float)i * (9.210340371976184f/512.0f));  // 10000^(-i/512)
    float ang = (float)s * th;
    float c = cosf(ang), sn = sinf(ang);
    orow[i]       = f2bf(xe*c - xo*sn);
    orow[i+512]   = f2bf(xe*sn + xo*c);
  }
}

// ---------------- GEMM: C[M][N] = A[M][K] @ Bt[N][K]^T, bf16 out ------------------
// BM=64 BN=128 BK=32, 4 waves (2x2, each 32x64), double-buffered LDS, 1 barrier/step.
__global__ __launch_bounds__(256) void k_gemm_t(
    const u16* __restrict__ A, const u16* __restrict__ Bt,
    u16* __restrict__ C, int M, int N, int K)
{
  __shared__ __align__(16) u16 As[2][64*32];
  __shared__ __align__(16) u16 Bs[2][128*32];
  int tid = threadIdx.x;
  int wave = tid>>6, lane = tid&63, l15 = lane&15, q = lane>>4;
  int wm = wave>>1, wn = wave&1;
  int m0 = blockIdx.y*64, n0 = blockIdx.x*128;
  const u16* ap  = A  + (size_t)(m0 + (tid>>2))*K + (tid&3)*8;
  const u16* bp0 = Bt + (size_t)(n0 + (tid>>2))*K + (tid&3)*8;
  const u16* bp1 = bp0 + (size_t)64*K;
  auto stage = [&](int buf, int k){
    gload16(ap  + k, &As[buf][wave*512]);
    gload16(bp0 + k, &Bs[buf][wave*512]);
    gload16(bp1 + k, &Bs[buf][2048 + wave*512]);
  };
  floatx4 acc[2][4];
  #pragma unroll
  for (int i=0;i<2;i++)
    #pragma unroll
    for (int j=0;j<4;j++) acc[i][j] = (floatx4){0.f,0.f,0.f,0.f};
  int NS = K/32, cur = 0;
  stage(0, 0);
  __syncthreads();
  for (int ks=0; ks<NS; ++ks){
    if (ks+1 < NS) stage(cur^1, (ks+1)*32);   // prefetch overlaps compute below
    short8 af[2], bf[4];
    #pragma unroll
    for (int i=0;i<2;i++) af[i] = *(const short8*)&As[cur][(wm*32 + i*16 + l15)*32 + q*8];
    #pragma unroll
    for (int i=0;i<4;i++) bf[i] = *(const short8*)&Bs[cur][(wn*64 + i*16 + l15)*32 + q*8];
    #pragma unroll
    for (int mi=0;mi<2;mi++)
      #pragma unroll
      for (int ni=0;ni<4;ni++)
        acc[mi][ni] = mfma16(af[mi], bf[ni], acc[mi][ni]);
    __syncthreads();                           // drains prefetch after compute
    cur ^= 1;
  }
  #pragma unroll
  for (int mi=0;mi<2;mi++)
    #pragma unroll
    for (int ni=0;ni<4;ni++)
      #pragma unroll
      for (int r=0;r<4;r++){
        int row = m0 + wm*32 + mi*16 + q*4 + r;   // C/D: row=(lane>>4)*4+reg, col=lane&15
        int col = n0 + wn*64 + ni*16 + l15;
        C[(size_t)row*N + col] = f2bf(acc[mi][ni][r]);
      }
}

// ---------------- same GEMM + fp32 residual -> fp32 h (acc) AND out ---------------
__global__ __launch_bounds__(256) void k_gemm_resid(
    const u16* __restrict__ A, const u16* __restrict__ Bt,
    const float* __restrict__ resid, float* __restrict__ hacc,
    float* __restrict__ out, int M, int N, int K)
{
  __shared__ __align__(16) u16 As[2][64*32];
  __shared__ __align__(16) u16 Bs[2][128*32];
  int tid = threadIdx.x;
  int wave = tid>>6, lane = tid&63, l15 = lane&15, q = lane>>4;
  int wm = wave>>1, wn = wave&1;
  int m0 = blockIdx.y*64, n0 = blockIdx.x*128;
  const u16* ap  = A  + (size_t)(m0 + (tid>>2))*K + (tid&3)*8;
  const u16* bp0 = Bt + (size_t)(n0 + (tid>>2))*K + (tid&3)*8;
  const u16* bp1 = bp0 + (size_t)64*K;
  auto stage = [&](int buf, int k){
    gload16(ap  + k, &As[buf][wave*512]);
    gload16(bp0 + k, &Bs[buf][wave*512]);
    gload16(bp1 + k, &Bs[buf][2048 + wave*512]);
  };
  floatx4 acc[2][4];
  #pragma unroll
  for (int i=0;i<2;i++)
    #pragma unroll
    for (int j=0;j<4;j++) acc[i][j] = (floatx4){0.f,0.f,0.f,0.f};
  int NS = K/32, cur = 0;
  stage(0, 0);
  __syncthreads();
  for (int ks=0; ks<NS; ++ks){
    if (ks+1 < NS) stage(cur^1, (ks+1)*32);
    short8 af[2], bf[4];
    #pragma unroll
    for (int i=0;i<2;i++) af[i] = *(const short8*)&As[cur][(wm*32 + i*16 + l15)*32 + q*8];
    #pragma unroll
    for (int i=0;i<4;i++) bf[i] = *(const short8*)&Bs[cur][(wn*64 + i*16 + l15)*32 + q*8];
    #pragma unroll
    for (int mi=0;mi<2;mi++)
      #pragma unroll
      for (int ni=0;ni<4;ni++)
        acc[mi][ni] = mfma16(af[mi], bf[ni], acc[mi][ni]);
    __syncthreads();
    cur ^= 1;
  }
  #pragma unroll
  for (int mi=0;mi<2;mi++)
    #pragma unroll
    for (int ni=0;ni<4;ni++)
      #pragma unroll
      for (int r=0;r<4;r++){
        int row = m0 + wm*32 + mi*16 + q*4 + r;
        int col = n0 + wn*64 + ni*16 + l15;
        size_t idx = (size_t)row*N + col;
        float v = acc[mi][ni][r] + resid[idx];
        hacc[idx] = v;
        out[idx]  = v;     // moe2 atomically accumulates expert output on top
      }
}

// ---------------- V transpose: qkv V-slice -> Vt[b][g][d][s] (LDS-tiled) ----------
__global__ __launch_bounds__(256) void k_vtrans(
    const u16* __restrict__ qkv, u16* __restrict__ Vt)
{
  int st = blockIdx.x;          // s-tile (SEQ/64)
  int bg = blockIdx.y;          // b*4+g
  int b = bg >> 2, g = bg & 3;
  int tid = threadIdx.x;
  __shared__ u16 tile[64*APAD];
  #pragma unroll
  for (int i=0;i<2;i++){
    int idx = i*256 + tid;
    int srow = idx >> 3, cch = (idx&7)*8;
    uint4 v = *(const uint4*)(qkv + (size_t)(b*SEQ + st*64 + srow)*QKVN
                              + D_MODEL + KVD + g*64 + cch);
    *(uint4*)&tile[srow*APAD + cch] = v;
  }
  __syncthreads();
  #pragma unroll
  for (int i=0;i<2;i++){
    int idx = i*256 + tid;
    int drow = idx >> 3, sch = (idx&7)*8;
    u16 tmp[8];
    #pragma unroll
    for (int j=0;j<8;j++) tmp[j] = tile[(sch+j)*APAD + drow];
    *(uint4*)(Vt + ((size_t)(bg*64 + drow))*SEQ + st*64 + sch) = *(uint4*)tmp;
  }
}

// ---------------- flash attention: 64-row Q-tile per block, MFMA QK^T & PV --------
__global__ __launch_bounds__(256) void k_attn_flash(
    const u16* __restrict__ qkv, const u16* __restrict__ Vt, u16* __restrict__ O)
{
  int qt = blockIdx.x, h = blockIdx.y, b = blockIdx.z;
  int g = h >> 2;
  int tid = threadIdx.x, wave = tid>>6, lane = tid&63, l15 = lane&15, q = lane>>4;
  __shared__ u16 Ks[64*APAD];
  __shared__ u16 Vs[64*APAD];        // transposed V tile: [d][key]
  __shared__ u16 Ps[4*16*APAD];      // per-wave P buffer

  int qbase = qt*64;
  const u16* qrow = qkv + (size_t)(b*SEQ + qbase + wave*16 + l15)*QKVN + h*64;
  short8 qa0 = *(const short8*)(qrow + q*8);
  short8 qa1 = *(const short8*)(qrow + 32 + q*8);

  floatx4 Of[4];
  #pragma unroll
  for (int nt=0;nt<4;nt++) Of[nt] = (floatx4){0.f,0.f,0.f,0.f};
  float mrun[4], lrun[4];
  #pragma unroll
  for (int r=0;r<4;r++){ mrun[r] = -1e30f; lrun[r] = 0.f; }

  for (int t=0; t<=qt; ++t){
    int kbase = t*64;
    __syncthreads();
    #pragma unroll
    for (int i=0;i<2;i++){
      int idx = i*256 + tid;
      int row = idx >> 3, cch = (idx&7)*8;
      uint4 kv = *(const uint4*)(qkv + (size_t)(b*SEQ + kbase + row)*QKVN
                                 + D_MODEL + g*64 + cch);
      *(uint4*)&Ks[row*APAD + cch] = kv;
      uint4 vv = *(const uint4*)(Vt + ((size_t)((b*4+g)*64 + row))*SEQ + kbase + cch);
      *(uint4*)&Vs[row*APAD + cch] = vv;
    }
    __syncthreads();

    floatx4 Sf[4];
    #pragma unroll
    for (int jt=0;jt<4;jt++){
      short8 bf0 = *(const short8*)&Ks[(jt*16+l15)*APAD + q*8];
      short8 bf1 = *(const short8*)&Ks[(jt*16+l15)*APAD + 32 + q*8];
      Sf[jt] = mfma16(qa0, bf0, (floatx4){0.f,0.f,0.f,0.f});
      Sf[jt] = mfma16(qa1, bf1, Sf[jt]);
    }
    bool maskt = (t == qt);
    #pragma unroll
    for (int r=0;r<4;r++){
      float s0 = Sf[0][r]*0.125f, s1 = Sf[1][r]*0.125f,
            s2 = Sf[2][r]*0.125f, s3 = Sf[3][r]*0.125f;
      if (maskt){
        int qg = qbase + wave*16 + q*4 + r;
        if (kbase +      l15 > qg) s0 = -1e30f;
        if (kbase + 16 + l15 > qg) s1 = -1e30f;
        if (kbase + 32 + l15 > qg) s2 = -1e30f;
        if (kbase + 48 + l15 > qg) s3 = -1e30f;
      }
      float mx = fmaxf(fmaxf(s0,s1), fmaxf(s2,s3));
      #pragma unroll
      for (int o=1;o<16;o<<=1) mx = fmaxf(mx, __shfl_xor(mx, o, 64));
      float mc = fmaxf(mrun[r], mx);
      float alpha = __expf(mrun[r]-mc);
      float p0 = __expf(s0-mc), p1 = __expf(s1-mc), p2 = __expf(s2-mc), p3 = __expf(s3-mc);
      float rs = p0+p1+p2+p3;
      #pragma unroll
      for (int o=1;o<16;o<<=1) rs += __shfl_xor(rs, o, 64);
      lrun[r] = lrun[r]*alpha + rs;
      mrun[r] = mc;
      #pragma unroll
      for (int nt=0;nt<4;nt++) Of[nt][r] *= alpha;
      int prow = wave*16*APAD + (q*4+r)*APAD;
      Ps[prow +      l15] = f2bf(p0);
      Ps[prow + 16 + l15] = f2bf(p1);
      Ps[prow + 32 + l15] = f2bf(p2);
      Ps[prow + 48 + l15] = f2bf(p3);
    }
    #pragma unroll
    for (int ks=0;ks<2;ks++){
      short8 pa = *(const short8*)&Ps[wave*16*APAD + l15*APAD + ks*32 + q*8];
      #pragma unroll
      for (int nt=0;nt<4;nt++){
        short8 vb = *(const short8*)&Vs[(nt*16+l15)*APAD + ks*32 + q*8];
        Of[nt] = mfma16(pa, vb, Of[nt]);
      }
    }
  }
  #pragma unroll
  for (int r=0;r<4;r++){
    float linv = 1.0f / lrun[r];
    int row = b*SEQ + qbase + wave*16 + q*4 + r;
    #pragma unroll
    for (int nt=0;nt<4;nt++){
      O[(size_t)row*D_MODEL + h*64 + nt*16 + l15] = f2bf(Of[nt][r]*linv);
    }
  }
}

// ---------------- rmsnorm2 (fp32 in, bf16 out) ----------------
__global__ __launch_bounds__(256) void k_rmsnorm2(
    const float* __restrict__ hacc, const float* __restrict__ w, u16* __restrict__ hn)
{
  int tok = blockIdx.x, tid = threadIdx.x;
  float4 v = ((const float4*)(hacc + (size_t)tok*D_MODEL))[tid];
  __shared__ float red[256];
  red[tid] = v.x*v.x + v.y*v.y + v.z*v.z + v.w*v.w;
  __syncthreads();
  for (int o=128;o>0;o>>=1){ if(tid<o) red[tid]+=red[tid+o]; __syncthreads(); }
  float inv = rsqrtf(red[0]*(1.0f/D_MODEL) + 1e-6f);
  int i = tid*4;
  float4 wv = ((const float4*)w)[tid];
  u16* orow = hn + (size_t)tok*D_MODEL;
  orow[i+0] = f2bf(v.x*inv*wv.x);
  orow[i+1] = f2bf(v.y*inv*wv.y);
  orow[i+2] = f2bf(v.z*inv*wv.z);
  orow[i+3] = f2bf(v.w*inv*wv.w);
}

// ---------------- router: one wave per token, FULL FP32 ----------------
__global__ __launch_bounds__(64) void k_router(
    const float* __restrict__ hacc, const float* __restrict__ w2,
    const float* __restrict__ rw, const float* __restrict__ rb,
    int* __restrict__ topi, float* __restrict__ topw)
{
  int tok = blockIdx.x, lane = threadIdx.x;
  const float* xrow = hacc + (size_t)tok*D_MODEL;
  float ss = 0.f;
  #pragma unroll
  for (int ii=0; ii<4; ii++){
    float4 v = ((const float4*)xrow)[lane + ii*64];
    ss += v.x*v.x + v.y*v.y + v.z*v.z + v.w*v.w;
  }
  #pragma unroll
  for (int o=32;o>0;o>>=1) ss += __shfl_down(ss, o, 64);
  ss = __shfl(ss, 0, 64);
  float inv = rsqrtf(ss*(1.0f/D_MODEL) + 1e-6f);
  float accv[8] = {0.f,0.f,0.f,0.f,0.f,0.f,0.f,0.f};
  for (int d = lane; d < D_MODEL; d += 64){
    float xv = xrow[d]*inv*w2[d];
    float4 r0 = ((const float4*)(rw + (size_t)d*8))[0];
    float4 r1 = ((const float4*)(rw + (size_t)d*8))[1];
    accv[0] += xv*r0.x; accv[1] += xv*r0.y;
    accv[2] += xv*r0.z; accv[3] += xv*r0.w;
    accv[4] += xv*r1.x; accv[5] += xv*r1.y;
    accv[6] += xv*r1.z; accv[7] += xv*r1.w;
  }
  #pragma unroll
  for (int e=0;e<8;e++){
    #pragma unroll
    for (int o=32;o>0;o>>=1) accv[e] += __shfl_down(accv[e], o, 64);
  }
  if (lane==0){
    float lg[8];
    #pragma unroll
    for (int e=0;e<8;e++) lg[e] = accv[e] + rb[e];
    int i0=0; float v0=lg[0];
    for (int e=1;e<8;e++) if (lg[e]>v0){v0=lg[e]; i0=e;}
    int i1=-1; float v1=-1e30f;
    for (int e=0;e<8;e++) if (e!=i0 && lg[e]>v1){v1=lg[e]; i1=e;}
    float e1 = __expf(v1-v0);
    float wsum = 1.f + e1;
    topi[tok*2+0]=i0; topi[tok*2+1]=i1;
    topw[tok*2+0]=1.f/wsum; topw[tok*2+1]=e1/wsum;
  }
}

// ---------------- pack: per-expert packed token lists (single block) --------------
__global__ __launch_bounds__(256) void k_pack(
    const int* __restrict__ topi, const float* __restrict__ topw,
    int* __restrict__ off, int* __restrict__ perm, float* __restrict__ pw)
{
  __shared__ int cnt[8], cur[8], offs[9];
  int tid = threadIdx.x;
  if (tid<8) cnt[tid]=0;
  __syncthreads();
  for (int i=tid;i<NTOK*2;i+=256) atomicAdd(&cnt[topi[i]],1);
  __syncthreads();
  if (tid==0){
    int s=0;
    for (int e=0;e<8;e++){ offs[e]=s; s+=cnt[e]; }
    offs[8]=s;
    for (int e=0;e<9;e++) off[e]=offs[e];
  }
  __syncthreads();
  if (tid<8) cur[tid]=offs[tid];
  __syncthreads();
  for (int i=tid;i<NTOK*2;i+=256){
    int e = topi[i];
    int pos = atomicAdd(&cur[e],1);
    perm[pos] = i>>1;
    pw[pos]   = topw[i];
  }
}

// ---------------- MoE stage1: H = silu(Xg@W1+b1)*(Xg@W2+b2), gathered rows --------
// BM=128 BN=64 dual-B, double-buffered LDS (32KB), 1 barrier/step.
__global__ __launch_bounds__(256) void k_moe1(
    const u16* __restrict__ hn,
    const u16* __restrict__ W1t, const float* __restrict__ b1,
    const u16* __restrict__ W2t, const float* __restrict__ b2,
    const int* __restrict__ off, const int* __restrict__ perm,
    u16* __restrict__ H)
{
  int e = blockIdx.z;
  int base = off[e], cnte = off[e+1]-base;
  int mt = blockIdx.y;
  if (mt*128 >= cnte) return;
  int n0 = blockIdx.x*64;
  __shared__ __align__(16) u16 As[2][128*32];
  __shared__ __align__(16) u16 B1s[2][64*32];
  __shared__ __align__(16) u16 B2s[2][64*32];
  int tid = threadIdx.x;
  int wave = tid>>6, lane = tid&63, l15 = lane&15, q = lane>>4;
  int wm = wave>>1, wn = wave&1;
  int r0 = mt*128 + (tid>>2), r1 = r0 + 64;
  int t0 = (r0 < cnte) ? perm[base+r0] : 0;
  int t1 = (r1 < cnte) ? perm[base+r1] : 0;
  const u16* ap0 = hn + (size_t)t0*D_MODEL + (tid&3)*8;
  const u16* ap1 = hn + (size_t)t1*D_MODEL + (tid&3)*8;
  const u16* b1p = W1t + (size_t)e*D_FF*D_MODEL + (size_t)(n0 + (tid>>2))*D_MODEL + (tid&3)*8;
  const u16* b2p = W2t + (size_t)e*D_FF*D_MODEL + (size_t)(n0 + (tid>>2))*D_MODEL + (tid&3)*8;
  auto stage = [&](int buf, int k){
    gload16(ap0 + k, &As[buf][wave*512]);
    gload16(ap1 + k, &As[buf][2048 + wave*512]);
    gload16(b1p + k, &B1s[buf][wave*512]);
    gload16(b2p + k, &B2s[buf][wave*512]);
  };
  floatx4 acc1[4][2], acc2[4][2];
  #pragma unroll
  for (int i=0;i<4;i++)
    #pragma unroll
    for (int j=0;j<2;j++){ acc1[i][j]=(floatx4){0.f,0.f,0.f,0.f}; acc2[i][j]=(floatx4){0.f,0.f,0.f,0.f}; }
  int cur = 0;
  stage(0, 0);
  __syncthreads();
  for (int ks=0; ks<D_MODEL/32; ++ks){
    if (ks+1 < D_MODEL/32) stage(cur^1, (ks+1)*32);
    short8 af[4], f1[2], f2[2];
    #pragma unroll
    for (int i=0;i<4;i++) af[i] = *(const short8*)&As[cur][(wm*64 + i*16 + l15)*32 + q*8];
    #pragma unroll
    for (int i=0;i<2;i++){
      f1[i] = *(const short8*)&B1s[cur][(wn*32 + i*16 + l15)*32 + q*8];
      f2[i] = *(const short8*)&B2s[cur][(wn*32 + i*16 + l15)*32 + q*8];
    }
    #pragma unroll
    for (int mi=0;mi<4;mi++)
      #pragma unroll
      for (int ni=0;ni<2;ni++){
        acc1[mi][ni] = mfma16(af[mi], f1[ni], acc1[mi][ni]);
        acc2[mi][ni] = mfma16(af[mi], f2[ni], acc2[mi][ni]);
      }
    __syncthreads();
    cur ^= 1;
  }
  #pragma unroll
  for (int mi=0;mi<4;mi++)
    #pragma unroll
    for (int ni=0;ni<2;ni++)
      #pragma unroll
      for (int r=0;r<4;r++){
        int rloc = wm*64 + mi*16 + q*4 + r;
        int grow = mt*128 + rloc;
        if (grow < cnte){
          int col = n0 + wn*32 + ni*16 + l15;
          float h1 = acc1[mi][ni][r] + b1[e*D_FF+col];
          float h2 = acc2[mi][ni][r] + b2[e*D_FF+col];
          float sil = h1 / (1.f + __expf(-h1));
          H[(size_t)(base + grow)*D_FF + col] = f2bf(h2*sil);
        }
      }
}

// ---------------- MoE stage2: out[token] += w * (H@W3 + b3) -----------------------
// BM=64 BN=128 split-K=2: ~4x active blocks vs round-1 (occupancy 10% -> ~50%).
// blockIdx.y = mt*2 + ksplit; each split covers K/2=2048; b3 added by split 0 only.
__global__ __launch_bounds__(256) void k_moe2(
    const u16* __restrict__ H, const u16* __restrict__ W3t, const float* __restrict__ b3,
    const int* __restrict__ off, const int* __restrict__ perm, const float* __restrict__ pw,
    float* __restrict__ out)
{
  int e = blockIdx.z;
  int base = off[e], cnte = off[e+1]-base;
  int mt = blockIdx.y >> 1;
  int ksp = blockIdx.y & 1;
  if (mt*64 >= cnte) return;
  int n0 = blockIdx.x*128;
  __shared__ __align__(16) u16 As[2][64*32];
  __shared__ __align__(16) u16 Bs[2][128*32];
  int tid = threadIdx.x;
  int wave = tid>>6, lane = tid&63, l15 = lane&15, q = lane>>4;
  int wm = wave>>1, wn = wave&1;
  // H rows are packed contiguous; overread past cnte stays inside workspace, masked.
  const u16* ap  = H + (size_t)(base + mt*64 + (tid>>2))*D_FF + ksp*2048 + (tid&3)*8;
  const u16* bp0 = W3t + (size_t)e*D_MODEL*D_FF + (size_t)(n0 + (tid>>2))*D_FF + ksp*2048 + (tid&3)*8;
  const u16* bp1 = bp0 + (size_t)64*D_FF;
  auto stage = [&](int buf, int k){
    gload16(ap  + k, &As[buf][wave*512]);
    gload16(bp0 + k, &Bs[buf][wave*512]);
    gload16(bp1 + k, &Bs[buf][2048 + wave*512]);
  };
  floatx4 acc[2][4];
  #pragma unroll
  for (int i=0;i<2;i++)
    #pragma unroll
    for (int j=0;j<4;j++) acc[i][j] = (floatx4){0.f,0.f,0.f,0.f};
  int cur = 0;
  stage(0, 0);
  __syncthreads();
  for (int ks=0; ks<64; ++ks){            // 2048/32 steps per split
    if (ks+1 < 64) stage(cur^1, (ks+1)*32);
    short8 af[2], bf[4];
    #pragma unroll
    for (int i=0;i<2;i++) af[i] = *(const short8*)&As[cur][(wm*32 + i*16 + l15)*32 + q*8];
    #pragma unroll
    for (int i=0;i<4;i++) bf[i] = *(const short8*)&Bs[cur][(wn*64 + i*16 + l15)*32 + q*8];
    #pragma unroll
    for (int mi=0;mi<2;mi++)
      #pragma unroll
      for (int ni=0;ni<4;ni++)
        acc[mi][ni] = mfma16(af[mi], bf[ni], acc[mi][ni]);
    __syncthreads();
    cur ^= 1;
  }
  #pragma unroll
  for (int mi=0;mi<2;mi++)
    #pragma unroll
    for (int ni=0;ni<4;ni++)
      #pragma unroll
      for (int r=0;r<4;r++){
        int grow = mt*64 + wm*32 + mi*16 + q*4 + r;
        if (grow < cnte){
          int col = n0 + wn*64 + ni*16 + l15;
          int tok = perm[base+grow];
          float wgt = pw[base+grow];
          float val = acc[mi][ni][r] + (ksp==0 ? b3[e*D_MODEL+col] : 0.f);
          atomicAdd(out + (size_t)tok*D_MODEL + col, wgt*val);
        }
      }
}

extern "C" void kernel_launch(void* const* d_in, const int* in_sizes, int n_in,
                              void* d_out, int out_size, void* d_ws, size_t ws_size,
                              hipStream_t stream)
{
  const float* x   = (const float*)d_in[0];
  const float* n1w = (const float*)d_in[1];
  const float* Wq  = (const float*)d_in[2];
  const float* Wk  = (const float*)d_in[3];
  const float* Wv  = (const float*)d_in[4];
  const float* Wo  = (const float*)d_in[5];
  const float* n2w = (const float*)d_in[6];
  const float* rw  = (const float*)d_in[7];
  const float* rb  = (const float*)d_in[8];
  const float* W1  = (const float*)d_in[9];
  const float* b1  = (const float*)d_in[10];
  const float* W2  = (const float*)d_in[11];
  const float* b2  = (const float*)d_in[12];
  const float* W3  = (const float*)d_in[13];
  const float* b3  = (const float*)d_in[14];
  float* out = (float*)d_out;

  char* p = (char*)d_ws;
  auto alloc = [&](size_t bytes)->char*{
    char* r = p; p += (bytes + 255) & ~(size_t)255; return r;
  };
  u16*   xr   = (u16*)  alloc((size_t)NTOK*D_MODEL*2);
  u16*   qkv  = (u16*)  alloc((size_t)NTOK*QKVN*2);    // fused [Q|K|V] activations
  u16*   Vt   = (u16*)  alloc((size_t)NTOK*KVD*2);     // transposed V: [b][g][d][s]
  u16*   attn = (u16*)  alloc((size_t)NTOK*D_MODEL*2);
  u16*   hn   = (u16*)  alloc((size_t)NTOK*D_MODEL*2);
  float* acc  = (float*)alloc((size_t)NTOK*D_MODEL*4);
  int*   topi = (int*)  alloc((size_t)NTOK*2*4);
  float* topw = (float*)alloc((size_t)NTOK*2*4);
  int*   off  = (int*)  alloc(64);
  int*   perm = (int*)  alloc((size_t)NTOK*2*4);
  float* pw   = (float*)alloc((size_t)NTOK*2*4);
  u16*   H    = (u16*)  alloc((size_t)NTOK*2*D_FF*2);
  // transposed bf16 weight copies [N][K]
  u16*   Wqkvt= (u16*)  alloc((size_t)QKVN*D_MODEL*2);
  u16*   Wot  = (u16*)  alloc((size_t)D_MODEL*D_MODEL*2);
  u16*   W1t  = (u16*)  alloc((size_t)N_EXPERTS*D_MODEL*D_FF*2);
  u16*   W2t  = (u16*)  alloc((size_t)N_EXPERTS*D_MODEL*D_FF*2);
  u16*   W3t  = (u16*)  alloc((size_t)N_EXPERTS*D_FF*D_MODEL*2);

  // 0. weight transpose-convert fp32 [K][N] -> bf16 [N][K]; Q|K|V fused into one
  k_cvt_t<<<dim3(D_MODEL/64, D_MODEL/64, 1), 256, 0, stream>>>(Wq, Wqkvt, D_MODEL, D_MODEL);
  k_cvt_t<<<dim3(KVD/64,     D_MODEL/64, 1), 256, 0, stream>>>(Wk, Wqkvt + (size_t)D_MODEL*D_MODEL, D_MODEL, KVD);
  k_cvt_t<<<dim3(KVD/64,     D_MODEL/64, 1), 256, 0, stream>>>(Wv, Wqkvt + (size_t)(D_MODEL+KVD)*D_MODEL, D_MODEL, KVD);
  k_cvt_t<<<dim3(D_MODEL/64, D_MODEL/64, 1), 256, 0, stream>>>(Wo, Wot, D_MODEL, D_MODEL);
  k_cvt_t<<<dim3(D_FF/64,    D_MODEL/64, N_EXPERTS), 256, 0, stream>>>(W1, W1t, D_MODEL, D_FF);
  k_cvt_t<<<dim3(D_FF/64,    D_MODEL/64, N_EXPERTS), 256, 0, stream>>>(W2, W2t, D_MODEL, D_FF);
  k_cvt_t<<<dim3(D_MODEL/64, D_FF/64,    N_EXPERTS), 256, 0, stream>>>(W3, W3t, D_FF, D_MODEL);

  // 1. norm1 + rope
  k_rmsnorm_rope<<<NTOK, 256, 0, stream>>>(x, n1w, xr);
  // 2. fused QKV projection (one GEMM, N=1536)
  k_gemm_t<<<dim3(QKVN/128, NTOK/64), 256, 0, stream>>>(xr, Wqkvt, qkv, NTOK, QKVN, D_MODEL);
  // 3. attention (flash, MFMA)
  k_vtrans<<<dim3(SEQ/64, BATCH*N_GROUPS), 256, 0, stream>>>(qkv, Vt);
  k_attn_flash<<<dim3(SEQ/64, N_HEADS, BATCH), 256, 0, stream>>>(qkv, Vt, attn);
  // 4. out proj + residual -> h (fp32, to acc for norm/router AND to out for moe2)
  k_gemm_resid<<<dim3(D_MODEL/128, NTOK/64), 256, 0, stream>>>(attn, Wot, x, acc, out, NTOK, D_MODEL, D_MODEL);
  // 5. norm2 (bf16 activations for expert GEMMs)
  k_rmsnorm2<<<NTOK, 256, 0, stream>>>(acc, n2w, hn);
  // 6. router (fp32, from fp32 residual) + pack
  k_router<<<NTOK, 64, 0, stream>>>(acc, n2w, rw, rb, topi, topw);
  k_pack<<<1, 256, 0, stream>>>(topi, topw, off, perm, pw);
  // 7. expert FFN (moe2 accumulates into out on top of residual)
  k_moe1<<<dim3(D_FF/64,     32, N_EXPERTS), 256, 0, stream>>>(hn, W1t, b1, W2t, b2, off, perm, H);
  k_moe2<<<dim3(D_MODEL/128, 128, N_EXPERTS), 256, 0, stream>>>(H, W3t, b3, off, perm, pw, out);
}